// Round 3
// baseline (159.653 us; speedup 1.0000x reference)
//
#include <hip/hip_runtime.h>
#include <stdint.h>

// MemoryEfficientBSpline: out[b,o,p] = sum_i sum_g hat_g(nx[b,i,p]) * coef[b,o,i,g]
// hat_g(nx) = max(0, 1 - |nx - g|), nx = (clamp(x,-1,1)+1)*2.5 in [0,5], G=6.
// Batched GEMM M=64(o) x N=36864(p) x K=384 via mfma_f32_16x16x32_f16.
//  - prep kernel: coef f32 -> cpre f16 in hardware-k order, 393 KB, L2-resident.
//    Chunk c (32 i's), slot s = ks*32 + q8*8 + j  <->  g = s>>5 (= ks), iof = s&31.
//  - main kernel: A-fragments loaded DIRECTLY from global cpre (16 full lines per
//    dwordx4 instr, no LDS, no barriers for A). Only nx goes through LDS.

typedef __fp16 half8_t __attribute__((ext_vector_type(8)));
typedef __fp16 half2_t __attribute__((ext_vector_type(2)));
typedef float f32x4 __attribute__((ext_vector_type(4)));

#define NBATCH 8
#define OD 64
#define ID 64
#define PIX 36864          // 192*192
#define NG 6
#define PT 192             // pixels per block tile
#define KI 32              // i per chunk
#define NCHUNK 2
#define KROW 384           // k extent per (b,o) row in cpre
#define PROW 196           // nx_lds row stride in floats (192+4, 16B-aligned)
#define PTILES (PIX / PT)  // 192

#define CPRE_BYTES (NBATCH * OD * KROW * 2)  // 393216

__global__ __launch_bounds__(256)
void prep_coef(const float* __restrict__ coef, __fp16* __restrict__ cpre) {
  int idx = blockIdx.x * 256 + threadIdx.x;  // 0 .. 196607
  int b = idx / (OD * KROW);
  int rem = idx % (OD * KROW);
  int o = rem / KROW;
  int k = rem % KROW;
  int c = k / 192;
  int s = k % 192;
  int g = s >> 5;
  int iof = s & 31;
  float v = coef[((size_t)(b * OD + o) * ID + c * KI + iof) * NG + g];
  cpre[idx] = (__fp16)v;  // writes coalesced
}

__global__ __launch_bounds__(256, 3)
void kan_mfma2(const float* __restrict__ x, const __fp16* __restrict__ cpre,
               float* __restrict__ out) {
  const int t = threadIdx.x;
  const int lane = t & 63;
  const int wave = t >> 6;   // p sub-range [wave*48, wave*48+48)
  const int q8 = lane >> 4;
  const int col = lane & 15;

  const int bid = blockIdx.x;
  const int b = bid / PTILES;
  const int p0 = (bid % PTILES) * PT;

  __shared__ float nx_lds[KI][PROW] __attribute__((aligned(16)));  // 25088 B

  f32x4 acc[4][3];
#pragma unroll
  for (int i = 0; i < 4; ++i)
#pragma unroll
    for (int j = 0; j < 3; ++j)
      acc[i][j] = (f32x4){0.f, 0.f, 0.f, 0.f};

  const float* xb = x + (size_t)b * ID * PIX + p0;
  const __fp16* caw = cpre + (size_t)b * OD * KROW + (size_t)col * KROW + q8 * 8;
  const int srow = t >> 3;        // 0..31: i-offset this thread stages
  const int pb = (t & 7) * 24;    // 0..168: p base (24 floats = 6 float4)

  // prefetch chunk 0's x
  f32x4 xv[6];
#pragma unroll
  for (int j = 0; j < 6; ++j)
    xv[j] = *(const f32x4*)(xb + (size_t)srow * PIX + pb + 4 * j);

#pragma unroll
  for (int c = 0; c < NCHUNK; ++c) {
    if (c > 0) __syncthreads();  // prev chunk's readers done

    // ---- transform + stage nx (conflict-free b128 writes, [iof][p]) ----
#pragma unroll
    for (int j = 0; j < 6; ++j) {
      f32x4 n;
#pragma unroll
      for (int r = 0; r < 4; ++r) {
        float v = fminf(fmaxf(xv[j][r], -1.f), 1.f);
        n[r] = (v + 1.f) * 2.5f;
      }
      *(f32x4*)&nx_lds[srow][pb + 4 * j] = n;
    }
    __syncthreads();

    // ---- prefetch next chunk's x while computing ----
    if (c + 1 < NCHUNK) {
#pragma unroll
      for (int j = 0; j < 6; ++j)
        xv[j] = *(const f32x4*)(xb + (size_t)(KI + srow) * PIX + pb + 4 * j);
    }

    // ---- my 8 nx values per p-subtile (iof = q8*8 + j), reused over 6 ks ----
    float nxv[3][8];
#pragma unroll
    for (int pti = 0; pti < 3; ++pti) {
      int p = wave * 48 + pti * 16 + col;
#pragma unroll
      for (int j = 0; j < 8; ++j)
        nxv[pti][j] = nx_lds[q8 * 8 + j][p];
    }

    const __fp16* cac = caw + c * 192;
#pragma unroll
    for (int ks = 0; ks < 6; ++ks) {  // g = ks
      half8_t af[4];
#pragma unroll
      for (int ot = 0; ot < 4; ++ot)
        af[ot] = *(const half8_t*)(cac + (size_t)(ot * 16) * KROW + ks * 32);

      const float gf = (float)ks;
#pragma unroll
      for (int pti = 0; pti < 3; ++pti) {
        union { half2_t h2[4]; half8_t v; } bu;
#pragma unroll
        for (int jj = 0; jj < 4; ++jj) {
          float h0 = fmaxf(0.f, 1.f - fabsf(nxv[pti][2 * jj] - gf));
          float h1 = fmaxf(0.f, 1.f - fabsf(nxv[pti][2 * jj + 1] - gf));
          bu.h2[jj] = __builtin_amdgcn_cvt_pkrtz(h0, h1);
        }
#pragma unroll
        for (int ot = 0; ot < 4; ++ot)
          acc[ot][pti] = __builtin_amdgcn_mfma_f32_16x16x32_f16(
              af[ot], bu.v, acc[ot][pti], 0, 0, 0);
      }
    }
  }

  // ---- epilogue: C row = q8*4 + reg, col = lane&15 ----
  float* ob = out + (size_t)b * OD * PIX + p0;
#pragma unroll
  for (int ot = 0; ot < 4; ++ot) {
#pragma unroll
    for (int pti = 0; pti < 3; ++pti) {
      int p = wave * 48 + pti * 16 + col;
#pragma unroll
      for (int r = 0; r < 4; ++r) {
        int o = ot * 16 + q8 * 4 + r;
        ob[(size_t)o * PIX + p] = acc[ot][pti][r];
      }
    }
  }
}

// ---------- fallback (proven R2 kernel) if ws too small for cpre ----------
#define AROW 104
#define XROW 18
__global__ __launch_bounds__(256, 2)
void kan_mfma_fb(const float* __restrict__ x, const float* __restrict__ coef,
                 float* __restrict__ out) {
  const int t = threadIdx.x;
  const int lane = t & 63;
  const int wave = t >> 6;
  const int q8 = lane >> 4;
  const int col = lane & 15;
  const int bid = blockIdx.x;
  const int b = bid / PTILES;
  const int p0 = (bid % PTILES) * PT;

  __shared__ __fp16 A_lds[OD][AROW] __attribute__((aligned(16)));
  __shared__ float nxf[PT][XROW] __attribute__((aligned(16)));

  f32x4 acc[4][3];
#pragma unroll
  for (int i = 0; i < 4; ++i)
#pragma unroll
    for (int j = 0; j < 3; ++j) acc[i][j] = (f32x4){0.f, 0.f, 0.f, 0.f};

  const float* xb = x + (size_t)b * ID * PIX + p0;
  const float* cb = coef + (size_t)b * OD * ID * NG;
  const int iof0 = (q8 & 1) * 8;
  const int ghalf = q8 >> 1;

  for (int c = 0; c < 4; ++c) {
    const int i0 = c * 16;
    __syncthreads();
#pragma unroll
    for (int j = 0; j < 12; ++j) {
      int lin = j * 256 + t;
      int p = lin % PT;
      int iof = lin / PT;
      float xvv = xb[(size_t)(i0 + iof) * PIX + p];
      xvv = fminf(fmaxf(xvv, -1.f), 1.f);
      nxf[p][iof] = (xvv + 1.f) * 2.5f;
    }
    {
      const int o = t >> 2;
      const int r0 = (t & 3) * 24;
      const float* crow = cb + o * (ID * NG) + i0 * NG + r0;
#pragma unroll
      for (int j = 0; j < 24; ++j) {
        int r = r0 + j;
        int iof = r / 6;
        int g = r - iof * 6;
        A_lds[o][g * 16 + iof] = (__fp16)crow[j];
      }
    }
    __syncthreads();

    float nxv[3][8];
#pragma unroll
    for (int pti = 0; pti < 3; ++pti) {
      int p = wave * 48 + pti * 16 + col;
#pragma unroll
      for (int j = 0; j < 8; ++j) nxv[pti][j] = nxf[p][iof0 + j];
    }
#pragma unroll
    for (int ks = 0; ks < 3; ++ks) {
      half8_t af[4];
#pragma unroll
      for (int ot = 0; ot < 4; ++ot)
        af[ot] = *(const half8_t*)&A_lds[ot * 16 + col][ks * 32 + q8 * 8];
      const float gf = (float)(2 * ks + ghalf);
#pragma unroll
      for (int pti = 0; pti < 3; ++pti) {
        union { half2_t h2[4]; half8_t v; } bu;
#pragma unroll
        for (int jj = 0; jj < 4; ++jj) {
          float h0 = fmaxf(0.f, 1.f - fabsf(nxv[pti][2 * jj] - gf));
          float h1 = fmaxf(0.f, 1.f - fabsf(nxv[pti][2 * jj + 1] - gf));
          bu.h2[jj] = __builtin_amdgcn_cvt_pkrtz(h0, h1);
        }
#pragma unroll
        for (int ot = 0; ot < 4; ++ot)
          acc[ot][pti] = __builtin_amdgcn_mfma_f32_16x16x32_f16(
              af[ot], bu.v, acc[ot][pti], 0, 0, 0);
      }
    }
  }
  float* ob = out + (size_t)b * OD * PIX + p0;
#pragma unroll
  for (int ot = 0; ot < 4; ++ot)
#pragma unroll
    for (int pti = 0; pti < 3; ++pti) {
      int p = wave * 48 + pti * 16 + col;
#pragma unroll
      for (int r = 0; r < 4; ++r)
        ob[(size_t)(ot * 16 + q8 * 4 + r) * PIX + p] = acc[ot][pti][r];
    }
}

extern "C" void kernel_launch(void* const* d_in, const int* in_sizes, int n_in,
                              void* d_out, int out_size, void* d_ws, size_t ws_size,
                              hipStream_t stream) {
  const float* x = (const float*)d_in[0];
  const float* coef = (const float*)d_in[1];
  float* out = (float*)d_out;
  if (ws_size >= (size_t)CPRE_BYTES) {
    __fp16* cpre = (__fp16*)d_ws;
    hipLaunchKernelGGL(prep_coef, dim3((NBATCH * OD * KROW) / 256), dim3(256), 0,
                       stream, coef, cpre);
    hipLaunchKernelGGL(kan_mfma2, dim3(NBATCH * PTILES), dim3(256), 0, stream, x,
                       cpre, out);
  } else {
    hipLaunchKernelGGL(kan_mfma_fb, dim3(NBATCH * PTILES), dim3(256), 0, stream,
                       x, coef, out);
  }
}